// Round 7
// baseline (210.607 us; speedup 1.0000x reference)
//
#include <hip/hip_runtime.h>
#include <stdint.h>

#define D_DIM 784
#define H_DIM 1024
#define B_DIM 256
#define NBIN  10
#define G_CH  8             // chunk length (i's per main block)
#define T_CH  98            // D_DIM / G_CH
#define BT    16            // batch tile per main block (fixed by MFMA M=16)
#define BF    4             // batch rows per k_pscan block
#define LOG2E 1.4426950408889634f

typedef _Float16 half8_t  __attribute__((ext_vector_type(8)));
typedef __fp16   fp16x2_t __attribute__((ext_vector_type(2)));
typedef float    float4_t __attribute__((ext_vector_type(4)));

// ---------- prep: Wt2[j][h] = W[h][j] * log2(e), LDS-tiled transpose ----------
__global__ void k_transpose(const float* __restrict__ W, float* __restrict__ Wt2) {
    __shared__ float t[64][65];
    int j0 = blockIdx.x * 64, h0 = blockIdx.y * 64;
    int tj = threadIdx.x & 63, tr = threadIdx.x >> 6;
    int j = j0 + tj;
    #pragma unroll
    for (int r = 0; r < 16; ++r) {
        int hh = tr * 16 + r;
        t[hh][tj] = (j < D_DIM) ? W[(size_t)(h0 + hh) * D_DIM + j] : 0.0f;
    }
    __syncthreads();
    #pragma unroll
    for (int r = 0; r < 16; ++r) {
        int jj = tr * 16 + r;
        int jo = j0 + jj;
        if (jo < D_DIM) Wt2[(size_t)jo * H_DIM + h0 + tj] = t[tj][jj] * LOG2E;
    }
}

// ---------- prep: V -> f16 MFMA B-fragment layout via LDS staging ----------
// VB[i][kk][lane][jj]: lane needs B[k = kk*32 + (lane>>4)*8 + jj][n = lane&15]
__global__ void k_vbprep(const float* __restrict__ V, _Float16* __restrict__ VB) {
    int i   = blockIdx.x;
    int tid = threadIdx.x;
    __shared__ __align__(16) float vsf[H_DIM * NBIN];   // 40 KB
    const float4* src = (const float4*)(V + (size_t)i * H_DIM * NBIN);
    #pragma unroll
    for (int q = 0; q < 10; ++q) {
        float4 v = src[q * 256 + tid];
        *((float4*)&vsf[(q * 256 + tid) * 4]) = v;
    }
    __syncthreads();
    #pragma unroll
    for (int q = 0; q < 8; ++q) {
        int pair = q * 256 + tid;          // (kk,l) pair 0..2047
        int kk = pair >> 6, l = pair & 63;
        int n = l & 15, hb = kk * 32 + ((l >> 4) & 3) * 8;
        union { _Float16 h[8]; uint4 u; } o;
        #pragma unroll
        for (int jj = 0; jj < 8; ++jj)
            o.h[jj] = (_Float16)((n < NBIN) ? vsf[(hb + jj) * NBIN + n] : 0.0f);
        ((uint4*)VB)[(size_t)i * 2048 + pair] = o.u;
    }
}

// ---------- fused partial-sum + exclusive scan: PA[t][b][h] = c*log2e + sum_{j<t*G} x*W2 ----------
template<typename CT>
__global__ void k_pscan(const float* __restrict__ Wt2, const int* __restrict__ x,
                        const float* __restrict__ c, CT* __restrict__ PA) {
    int b0 = blockIdx.x * BF;
    int h  = blockIdx.y * 256 + threadIdx.x;
    __shared__ float xs[BF][D_DIM];
    for (int q = threadIdx.x; q < BF * (D_DIM / 4); q += 256) {
        int bb = q / (D_DIM / 4), r = q % (D_DIM / 4);
        int4 xi = ((const int4*)(x + (size_t)(b0 + bb) * D_DIM))[r];
        float4 xf = make_float4((float)xi.x, (float)xi.y, (float)xi.z, (float)xi.w);
        *((float4*)&xs[bb][r * 4]) = xf;
    }
    float acc[BF];
    float cv = c[h] * LOG2E;
    #pragma unroll
    for (int bb = 0; bb < BF; ++bb) acc[bb] = cv;
    __syncthreads();
    for (int t = 0; t < T_CH; ++t) {
        #pragma unroll
        for (int bb = 0; bb < BF; ++bb)
            PA[((size_t)t * B_DIM + b0 + bb) * H_DIM + h] = (CT)acc[bb];
        #pragma unroll
        for (int j = 0; j < G_CH; ++j) {
            float wv = Wt2[(size_t)(t * G_CH + j) * H_DIM + h];
            #pragma unroll
            for (int bb = 0; bb < BF; ++bb)
                acc[bb] += xs[bb][t * G_CH + j] * wv;
        }
    }
}

// ---------- main fused kernel ----------
// bounds(256,2): empirical compiler VGPR cap ≈ 256/N -> ~128. Need ~115 live
// (a[64] + vb[32] across deferred softmax). <=128 keeps 4 waves/SIMD.
template<typename CT>
__global__ __launch_bounds__(256, 2)
void k_main(const float* __restrict__ Wt2, const _Float16* __restrict__ VB,
            const CT* __restrict__ PA, const int* __restrict__ x,
            const float* __restrict__ bias, float* __restrict__ out) {
    int bt  = blockIdx.x;        // batch tile 0..15 (fast dim: VB L2 reuse)
    int tc  = blockIdx.y;        // chunk 0..97
    int tid = threadIdx.x;
    int w   = tid >> 6;          // wave 0..3 (K-split of H)
    int l   = tid & 63;
    int bl  = l & 15;            // MFMA A row == batch row within tile
    int kg  = l >> 4;            // 0..3
    int bg  = bt * BT + bl;
    int i0  = tc * G_CH;

    __shared__ __align__(16) float wlds[G_CH][H_DIM]; // 32 KB: Wt2 chunk
    __shared__ float red[2][4][64][5];               // ping-pong, stride-5 pad (10.25 KB)
    __shared__ float bs[G_CH][16];                   // 0.5 KB
    __shared__ __align__(16) float plds[BT][NBIN][12]; // 7.7 KB

    {   // stage bias chunk
        int ii = tid >> 4, n = tid & 15;
        if (ii < G_CH) bs[ii][n] = (n < NBIN) ? bias[(size_t)(i0 + ii) * NBIN + n] : 0.0f;
    }
    {   // stage Wt2 chunk rows i0..i0+7 (coalesced float4)
        #pragma unroll
        for (int r = 0; r < G_CH; ++r) {
            float4 v = ((const float4*)(Wt2 + (size_t)(i0 + r) * H_DIM))[tid];
            *((float4*)&wlds[r][tid * 4]) = v;
        }
    }
    // preload this lane's x values for the chunk (16B-aligned: i0 % 8 == 0)
    float xvf[G_CH];
    {
        const int4* xp = (const int4*)(x + (size_t)bg * D_DIM + i0);
        int4 x0 = xp[0], x1 = xp[1];
        xvf[0] = (float)x0.x; xvf[1] = (float)x0.y; xvf[2] = (float)x0.z; xvf[3] = (float)x0.w;
        xvf[4] = (float)x1.x; xvf[5] = (float)x1.y; xvf[6] = (float)x1.z; xvf[7] = (float)x1.w;
    }
    // checkpoint a-state: thread owns h = w*256 + m*32 + kg*8 + j (MFMA A-frag order)
    float a[8][8];
    {
        const CT* src = PA + ((size_t)tc * B_DIM + bg) * H_DIM + w * 256 + kg * 8;
        #pragma unroll
        for (int m = 0; m < 8; ++m)
            #pragma unroll
            for (int j = 0; j < 8; ++j)
                a[m][j] = (float)src[m * 32 + j];
    }
    __syncthreads();

    const uint4* vbbase = (const uint4*)VB;
    #pragma unroll 1
    for (int ii = 0; ii < G_CH; ++ii) {
        int i = i0 + ii;
        int par = ii & 1;

        // issue B-fragment loads for this i (consumed mid-m-loop)
        uint4 vb[8];
        const uint4* vbp = vbbase + ((size_t)i * 32 + w * 8) * 64 + l;
        #pragma unroll
        for (int m = 0; m < 8; ++m) vb[m] = vbp[m * 64];

        if (ii > 0) {   // deferred softmax for i-1 (overlaps vb latency)
            int ip = ii - 1, pp = par ^ 1;
            float tot = red[pp][0][l][w] + red[pp][1][l][w] + red[pp][2][l][w] + red[pp][3][l][w];
            int n = bl;
            float v = (n < NBIN) ? tot + bs[ip][n] : -3.0e38f;
            float vm = v;
            vm = fmaxf(vm, __shfl_xor(vm, 1));
            vm = fmaxf(vm, __shfl_xor(vm, 2));
            vm = fmaxf(vm, __shfl_xor(vm, 4));
            vm = fmaxf(vm, __shfl_xor(vm, 8));
            float e = __builtin_amdgcn_exp2f((v - vm) * LOG2E);
            float ss = e;
            ss += __shfl_xor(ss, 1); ss += __shfl_xor(ss, 2);
            ss += __shfl_xor(ss, 4); ss += __shfl_xor(ss, 8);
            float p = e * __builtin_amdgcn_rcpf(ss);
            if (n < NBIN) plds[kg * 4 + w][n][ip] = p;
        }

        float xf = xvf[ii];
        float4_t cfrag = {0.f, 0.f, 0.f, 0.f};
        #pragma unroll
        for (int m = 0; m < 8; ++m) {
            // sigmoid of CURRENT a (pre-update) -> f16 A-frag
            union { half8_t h8; uint u32[4]; } af;
            #pragma unroll
            for (int p = 0; p < 4; ++p) {
                float s0 = __builtin_amdgcn_rcpf(1.0f + __builtin_amdgcn_exp2f(-a[m][2 * p]));
                float s1 = __builtin_amdgcn_rcpf(1.0f + __builtin_amdgcn_exp2f(-a[m][2 * p + 1]));
                union { fp16x2_t v; uint u; } cv;
                cv.v = __builtin_amdgcn_cvt_pkrtz(s0, s1);
                af.u32[p] = cv.u;
            }
            union { half8_t h8; uint4 u; } bf;
            bf.u = vb[m];
            cfrag = __builtin_amdgcn_mfma_f32_16x16x32_f16(af.h8, bf.h8, cfrag, 0, 0, 0);

            // rank-1 update from LDS-staged Wt2 (conflict-free: quad-broadcast)
            const float4* wrow = (const float4*)&wlds[ii][w * 256 + kg * 8];
            float4 w0 = wrow[m * 8];
            float4 w1 = wrow[m * 8 + 1];
            a[m][0] += xf * w0.x; a[m][1] += xf * w0.y; a[m][2] += xf * w0.z; a[m][3] += xf * w0.w;
            a[m][4] += xf * w1.x; a[m][5] += xf * w1.y; a[m][6] += xf * w1.z; a[m][7] += xf * w1.w;
        }

        // publish C partials; ONE barrier per ii (ping-pong makes it safe)
        red[par][w][l][0] = cfrag[0]; red[par][w][l][1] = cfrag[1];
        red[par][w][l][2] = cfrag[2]; red[par][w][l][3] = cfrag[3];
        __syncthreads();
    }
    {   // softmax for last i (in red[(G_CH-1)&1] = red[1])
        int ip = G_CH - 1, pp = (G_CH - 1) & 1;
        float tot = red[pp][0][l][w] + red[pp][1][l][w] + red[pp][2][l][w] + red[pp][3][l][w];
        int n = bl;
        float v = (n < NBIN) ? tot + bs[ip][n] : -3.0e38f;
        float vm = v;
        vm = fmaxf(vm, __shfl_xor(vm, 1));
        vm = fmaxf(vm, __shfl_xor(vm, 2));
        vm = fmaxf(vm, __shfl_xor(vm, 4));
        vm = fmaxf(vm, __shfl_xor(vm, 8));
        float e = __builtin_amdgcn_exp2f((v - vm) * LOG2E);
        float ss = e;
        ss += __shfl_xor(ss, 1); ss += __shfl_xor(ss, 2);
        ss += __shfl_xor(ss, 4); ss += __shfl_xor(ss, 8);
        float p = e * __builtin_amdgcn_rcpf(ss);
        if (n < NBIN) plds[kg * 4 + w][n][ip] = p;
    }
    __syncthreads();

    // coalesced chunk writeback: out[b][n][i0..i0+7]
    if (tid < BT * NBIN) {
        int bb = tid / NBIN, n = tid % NBIN;
        size_t base = ((size_t)(bt * BT + bb) * NBIN + n) * D_DIM + i0;
        #pragma unroll
        for (int q = 0; q < 2; ++q) {
            float4 v = *((float4*)&plds[bb][n][q * 4]);
            *((float4*)(out + base + q * 4)) = v;
        }
    }
}

extern "C" void kernel_launch(void* const* d_in, const int* in_sizes, int n_in,
                              void* d_out, int out_size, void* d_ws, size_t ws_size,
                              hipStream_t stream) {
    const int*   x    = (const int*)d_in[0];
    const float* W    = (const float*)d_in[1];
    const float* c    = (const float*)d_in[2];
    const float* V    = (const float*)d_in[3];
    const float* bias = (const float*)d_in[4];
    float* out = (float*)d_out;

    char* ws = (char*)d_ws;
    size_t off = 0;
    float* Wt2 = (float*)(ws + off);
    off += (size_t)D_DIM * H_DIM * sizeof(float);
    off = (off + 255) & ~(size_t)255;
    _Float16* VB = (_Float16*)(ws + off);
    off += (size_t)D_DIM * 32 * 64 * 8 * sizeof(_Float16);
    off = (off + 255) & ~(size_t)255;
    size_t pa_f32 = (size_t)T_CH * B_DIM * H_DIM * sizeof(float);
    bool f32ck = (off + pa_f32) <= ws_size;

    k_transpose<<<dim3(13, 16), 256, 0, stream>>>(W, Wt2);
    k_vbprep<<<dim3(D_DIM), 256, 0, stream>>>(V, VB);

    if (f32ck) {
        float* PA = (float*)(ws + off);
        k_pscan<float><<<dim3(B_DIM / BF, 4), 256, 0, stream>>>(Wt2, x, c, PA);
        k_main<float><<<dim3(B_DIM / BT, T_CH), 256, 0, stream>>>(Wt2, VB, PA, x, bias, out);
    } else {
        _Float16* PA = (_Float16*)(ws + off);
        k_pscan<_Float16><<<dim3(B_DIM / BF, 4), 256, 0, stream>>>(Wt2, x, c, PA);
        k_main<_Float16><<<dim3(B_DIM / BT, T_CH), 256, 0, stream>>>(Wt2, VB, PA, x, bias, out);
    }
}

// Round 8
// 202.089 us; speedup vs baseline: 1.0421x; 1.0421x over previous
//
#include <hip/hip_runtime.h>
#include <stdint.h>

#define D_DIM 784
#define H_DIM 1024
#define B_DIM 256
#define NBIN  10
#define G_CH  8             // chunk length (i's per main block)
#define T_CH  98            // D_DIM / G_CH
#define BT    16            // batch tile per main block (fixed by MFMA M=16)
#define BF    2             // batch rows per k_pscan block
#define LOG2E 1.4426950408889634f

typedef _Float16 half8_t  __attribute__((ext_vector_type(8)));
typedef __fp16   fp16x2_t __attribute__((ext_vector_type(2)));
typedef float    float4_t __attribute__((ext_vector_type(4)));

// ---------- prep: Wt2[j][h] = W[h][j] * log2(e), LDS-tiled transpose ----------
__global__ void k_transpose(const float* __restrict__ W, float* __restrict__ Wt2) {
    __shared__ float t[64][65];
    int j0 = blockIdx.x * 64, h0 = blockIdx.y * 64;
    int tj = threadIdx.x & 63, tr = threadIdx.x >> 6;
    int j = j0 + tj;
    #pragma unroll
    for (int r = 0; r < 16; ++r) {
        int hh = tr * 16 + r;
        t[hh][tj] = (j < D_DIM) ? W[(size_t)(h0 + hh) * D_DIM + j] : 0.0f;
    }
    __syncthreads();
    #pragma unroll
    for (int r = 0; r < 16; ++r) {
        int jj = tr * 16 + r;
        int jo = j0 + jj;
        if (jo < D_DIM) Wt2[(size_t)jo * H_DIM + h0 + tj] = t[tj][jj] * LOG2E;
    }
}

// ---------- prep: V -> f16 MFMA B-fragment layout via LDS staging ----------
// VB[i][kk][lane][jj]: lane needs B[k = kk*32 + (lane>>4)*8 + jj][n = lane&15]
__global__ void k_vbprep(const float* __restrict__ V, _Float16* __restrict__ VB) {
    int i   = blockIdx.x;
    int tid = threadIdx.x;
    __shared__ __align__(16) float vsf[H_DIM * NBIN];   // 40 KB
    const float4* src = (const float4*)(V + (size_t)i * H_DIM * NBIN);
    #pragma unroll
    for (int q = 0; q < 10; ++q) {
        float4 v = src[q * 256 + tid];
        *((float4*)&vsf[(q * 256 + tid) * 4]) = v;
    }
    __syncthreads();
    #pragma unroll
    for (int q = 0; q < 8; ++q) {
        int pair = q * 256 + tid;          // (kk,l) pair 0..2047
        int kk = pair >> 6, l = pair & 63;
        int n = l & 15, hb = kk * 32 + ((l >> 4) & 3) * 8;
        union { _Float16 h[8]; uint4 u; } o;
        #pragma unroll
        for (int jj = 0; jj < 8; ++jj)
            o.h[jj] = (_Float16)((n < NBIN) ? vsf[(hb + jj) * NBIN + n] : 0.0f);
        ((uint4*)VB)[(size_t)i * 2048 + pair] = o.u;
    }
}

// ---------- fused partial-sum + exclusive scan: PA[t][b][h] = c*log2e + sum_{j<t*G} x*W2 ----------
// PA stored f16: ulp grows with |a| exactly where sigmoid' vanishes -> error safe.
__global__ void k_pscan(const float* __restrict__ Wt2, const int* __restrict__ x,
                        const float* __restrict__ c, _Float16* __restrict__ PA) {
    int b0 = blockIdx.x * BF;
    int h  = blockIdx.y * 256 + threadIdx.x;
    __shared__ float xs[BF][D_DIM];
    for (int q = threadIdx.x; q < BF * (D_DIM / 4); q += 256) {
        int bb = q / (D_DIM / 4), r = q % (D_DIM / 4);
        int4 xi = ((const int4*)(x + (size_t)(b0 + bb) * D_DIM))[r];
        float4 xf = make_float4((float)xi.x, (float)xi.y, (float)xi.z, (float)xi.w);
        *((float4*)&xs[bb][r * 4]) = xf;
    }
    float acc0 = c[h] * LOG2E, acc1 = acc0;
    __syncthreads();
    for (int t = 0; t < T_CH; ++t) {
        PA[((size_t)t * B_DIM + b0 + 0) * H_DIM + h] = (_Float16)acc0;
        PA[((size_t)t * B_DIM + b0 + 1) * H_DIM + h] = (_Float16)acc1;
        #pragma unroll
        for (int j = 0; j < G_CH; ++j) {
            float wv = Wt2[(size_t)(t * G_CH + j) * H_DIM + h];
            acc0 += xs[0][t * G_CH + j] * wv;
            acc1 += xs[1][t * G_CH + j] * wv;
        }
    }
}

// ---------- main fused kernel ----------
// LDS 34.8 KB (f16 wlds) -> 4 blocks/CU; VGPR ~70 (cap 128 via bounds(256,2)).
__global__ __launch_bounds__(256, 2)
void k_main(const float* __restrict__ Wt2, const _Float16* __restrict__ VB,
            const _Float16* __restrict__ PA, const int* __restrict__ x,
            const float* __restrict__ bias, float* __restrict__ out) {
    int bt  = blockIdx.x;        // batch tile 0..15 (fast dim: VB L2 reuse)
    int tc  = blockIdx.y;        // chunk 0..97
    int tid = threadIdx.x;
    int w   = tid >> 6;          // wave 0..3 (K-split of H)
    int l   = tid & 63;
    int bl  = l & 15;            // MFMA A row == batch row within tile
    int kg  = l >> 4;            // 0..3
    int bg  = bt * BT + bl;
    int i0  = tc * G_CH;

    __shared__ __align__(16) _Float16 wlds[G_CH][H_DIM]; // 16 KB: Wt2 chunk (f16)
    __shared__ float red[2][4][64][5];               // ping-pong, stride-5 pad (10.25 KB)
    __shared__ float bs[G_CH][16];                   // 0.5 KB
    __shared__ __align__(16) float plds[BT][NBIN][12]; // 7.7 KB

    {   // stage bias chunk
        int ii = tid >> 4, n = tid & 15;
        if (ii < G_CH) bs[ii][n] = (n < NBIN) ? bias[(size_t)(i0 + ii) * NBIN + n] : 0.0f;
    }
    {   // stage Wt2 chunk rows i0..i0+7 as f16 (coalesced; ds_write_b64 2-way = free)
        #pragma unroll
        for (int r = 0; r < G_CH; ++r) {
            float4 v = ((const float4*)(Wt2 + (size_t)(i0 + r) * H_DIM))[tid];
            union { fp16x2_t v2[2]; uint2 u; } cv;
            cv.v2[0] = __builtin_amdgcn_cvt_pkrtz(v.x, v.y);
            cv.v2[1] = __builtin_amdgcn_cvt_pkrtz(v.z, v.w);
            *((uint2*)&wlds[r][tid * 4]) = cv.u;
        }
    }
    // preload this lane's x values for the chunk (16B-aligned: i0 % 8 == 0)
    float xvf[G_CH];
    {
        const int4* xp = (const int4*)(x + (size_t)bg * D_DIM + i0);
        int4 x0 = xp[0], x1 = xp[1];
        xvf[0] = (float)x0.x; xvf[1] = (float)x0.y; xvf[2] = (float)x0.z; xvf[3] = (float)x0.w;
        xvf[4] = (float)x1.x; xvf[5] = (float)x1.y; xvf[6] = (float)x1.z; xvf[7] = (float)x1.w;
    }
    // checkpoint a-state (f16, 16B vector loads): h = w*256 + m*32 + kg*8 + j
    float a[8][8];
    {
        const _Float16* src = PA + ((size_t)tc * B_DIM + bg) * H_DIM + w * 256 + kg * 8;
        #pragma unroll
        for (int m = 0; m < 8; ++m) {
            half8_t av = *((const half8_t*)(src + m * 32));
            #pragma unroll
            for (int j = 0; j < 8; ++j) a[m][j] = (float)av[j];
        }
    }
    __syncthreads();

    const uint4* vbbase = (const uint4*)VB;
    #pragma unroll 1
    for (int ii = 0; ii < G_CH; ++ii) {
        int i = i0 + ii;
        int par = ii & 1;

        // issue B-fragment loads for this i (consumed mid-m-loop)
        uint4 vb[8];
        const uint4* vbp = vbbase + ((size_t)i * 32 + w * 8) * 64 + l;
        #pragma unroll
        for (int m = 0; m < 8; ++m) vb[m] = vbp[m * 64];

        if (ii > 0) {   // deferred softmax for i-1 (overlaps vb latency)
            int ip = ii - 1, pp = par ^ 1;
            float tot = red[pp][0][l][w] + red[pp][1][l][w] + red[pp][2][l][w] + red[pp][3][l][w];
            int n = bl;
            float v = (n < NBIN) ? tot + bs[ip][n] : -3.0e38f;
            float vm = v;
            vm = fmaxf(vm, __shfl_xor(vm, 1));
            vm = fmaxf(vm, __shfl_xor(vm, 2));
            vm = fmaxf(vm, __shfl_xor(vm, 4));
            vm = fmaxf(vm, __shfl_xor(vm, 8));
            float e = __builtin_amdgcn_exp2f((v - vm) * LOG2E);
            float ss = e;
            ss += __shfl_xor(ss, 1); ss += __shfl_xor(ss, 2);
            ss += __shfl_xor(ss, 4); ss += __shfl_xor(ss, 8);
            float p = e * __builtin_amdgcn_rcpf(ss);
            if (n < NBIN) plds[kg * 4 + w][n][ip] = p;
        }

        float xf = xvf[ii];
        float4_t cfrag = {0.f, 0.f, 0.f, 0.f};
        #pragma unroll
        for (int m = 0; m < 8; ++m) {
            // sigmoid of CURRENT a (pre-update) -> f16 A-frag
            union { half8_t h8; uint u32[4]; } af;
            #pragma unroll
            for (int p = 0; p < 4; ++p) {
                float s0 = __builtin_amdgcn_rcpf(1.0f + __builtin_amdgcn_exp2f(-a[m][2 * p]));
                float s1 = __builtin_amdgcn_rcpf(1.0f + __builtin_amdgcn_exp2f(-a[m][2 * p + 1]));
                union { fp16x2_t v; uint u; } cv;
                cv.v = __builtin_amdgcn_cvt_pkrtz(s0, s1);
                af.u32[p] = cv.u;
            }
            union { half8_t h8; uint4 u; } bf;
            bf.u = vb[m];
            cfrag = __builtin_amdgcn_mfma_f32_16x16x32_f16(af.h8, bf.h8, cfrag, 0, 0, 0);

            // rank-1 update from f16 LDS Wt2 (one ds_read_b128, quad-broadcast; fma-mix)
            half8_t wh = *((const half8_t*)&wlds[ii][w * 256 + kg * 8 + m * 32]);
            a[m][0] += xf * (float)wh[0]; a[m][1] += xf * (float)wh[1];
            a[m][2] += xf * (float)wh[2]; a[m][3] += xf * (float)wh[3];
            a[m][4] += xf * (float)wh[4]; a[m][5] += xf * (float)wh[5];
            a[m][6] += xf * (float)wh[6]; a[m][7] += xf * (float)wh[7];
        }

        // publish C partials; ONE barrier per ii (ping-pong makes it safe)
        red[par][w][l][0] = cfrag[0]; red[par][w][l][1] = cfrag[1];
        red[par][w][l][2] = cfrag[2]; red[par][w][l][3] = cfrag[3];
        __syncthreads();
    }
    {   // softmax for last i
        int ip = G_CH - 1, pp = (G_CH - 1) & 1;
        float tot = red[pp][0][l][w] + red[pp][1][l][w] + red[pp][2][l][w] + red[pp][3][l][w];
        int n = bl;
        float v = (n < NBIN) ? tot + bs[ip][n] : -3.0e38f;
        float vm = v;
        vm = fmaxf(vm, __shfl_xor(vm, 1));
        vm = fmaxf(vm, __shfl_xor(vm, 2));
        vm = fmaxf(vm, __shfl_xor(vm, 4));
        vm = fmaxf(vm, __shfl_xor(vm, 8));
        float e = __builtin_amdgcn_exp2f((v - vm) * LOG2E);
        float ss = e;
        ss += __shfl_xor(ss, 1); ss += __shfl_xor(ss, 2);
        ss += __shfl_xor(ss, 4); ss += __shfl_xor(ss, 8);
        float p = e * __builtin_amdgcn_rcpf(ss);
        if (n < NBIN) plds[kg * 4 + w][n][ip] = p;
    }
    __syncthreads();

    // coalesced chunk writeback: out[b][n][i0..i0+7]
    if (tid < BT * NBIN) {
        int bb = tid / NBIN, n = tid % NBIN;
        size_t base = ((size_t)(bt * BT + bb) * NBIN + n) * D_DIM + i0;
        #pragma unroll
        for (int q = 0; q < 2; ++q) {
            float4 v = *((float4*)&plds[bb][n][q * 4]);
            *((float4*)(out + base + q * 4)) = v;
        }
    }
}

extern "C" void kernel_launch(void* const* d_in, const int* in_sizes, int n_in,
                              void* d_out, int out_size, void* d_ws, size_t ws_size,
                              hipStream_t stream) {
    const int*   x    = (const int*)d_in[0];
    const float* W    = (const float*)d_in[1];
    const float* c    = (const float*)d_in[2];
    const float* V    = (const float*)d_in[3];
    const float* bias = (const float*)d_in[4];
    float* out = (float*)d_out;

    char* ws = (char*)d_ws;
    size_t off = 0;
    float* Wt2 = (float*)(ws + off);
    off += (size_t)D_DIM * H_DIM * sizeof(float);
    off = (off + 255) & ~(size_t)255;
    _Float16* VB = (_Float16*)(ws + off);
    off += (size_t)D_DIM * 32 * 64 * 8 * sizeof(_Float16);
    off = (off + 255) & ~(size_t)255;
    _Float16* PA = (_Float16*)(ws + off);

    k_transpose<<<dim3(13, 16), 256, 0, stream>>>(W, Wt2);
    k_vbprep<<<dim3(D_DIM), 256, 0, stream>>>(V, VB);
    k_pscan<<<dim3(B_DIM / BF, 4), 256, 0, stream>>>(Wt2, x, c, PA);
    k_main<<<dim3(B_DIM / BT, T_CH), 256, 0, stream>>>(Wt2, VB, PA, x, bias, out);
}

// Round 9
// 187.684 us; speedup vs baseline: 1.1221x; 1.0767x over previous
//
#include <hip/hip_runtime.h>
#include <stdint.h>

#define D_DIM 784
#define H_DIM 1024
#define B_DIM 256
#define NBIN  10
#define G_CH  8             // chunk length (i's per main block)
#define T_CH  98            // D_DIM / G_CH
#define BT    16            // batch tile per main block (fixed by MFMA M=16)
#define BF    2             // batch rows per k_pscan block
#define LOG2E 1.4426950408889634f

typedef _Float16 half8_t  __attribute__((ext_vector_type(8)));
typedef __fp16   fp16x2_t __attribute__((ext_vector_type(2)));
typedef float    float4_t __attribute__((ext_vector_type(4)));

// ---------- fused prep: V->VB fragments (blocks 0..783) + W->Wt2h f16 transpose (blocks 784..991) ----------
__global__ void k_prep(const float* __restrict__ W, const float* __restrict__ V,
                       _Float16* __restrict__ Wt2h, _Float16* __restrict__ VB) {
    __shared__ __align__(16) float smem[H_DIM * NBIN];   // 40 KB, aliased by both branches
    int tid = threadIdx.x;
    if (blockIdx.x < D_DIM) {
        int i = blockIdx.x;
        const float4* src = (const float4*)(V + (size_t)i * H_DIM * NBIN);
        #pragma unroll
        for (int q = 0; q < 10; ++q) {
            float4 v = src[q * 256 + tid];
            *((float4*)&smem[(q * 256 + tid) * 4]) = v;
        }
        __syncthreads();
        #pragma unroll
        for (int q = 0; q < 8; ++q) {
            int pair = q * 256 + tid;          // (kk,l) pair 0..2047
            int kk = pair >> 6, l = pair & 63;
            int n = l & 15, hb = kk * 32 + ((l >> 4) & 3) * 8;
            union { _Float16 h[8]; uint4 u; } o;
            #pragma unroll
            for (int jj = 0; jj < 8; ++jj)
                o.h[jj] = (_Float16)((n < NBIN) ? smem[(hb + jj) * NBIN + n] : 0.0f);
            ((uint4*)VB)[(size_t)i * 2048 + pair] = o.u;
        }
    } else {
        int q = blockIdx.x - D_DIM;            // 0..207
        int j0 = (q % 13) * 64, h0 = (q / 13) * 64;
        float (*t)[65] = (float(*)[65])smem;   // 16.6 KB view
        int tj = tid & 63, tr = tid >> 6;
        int j = j0 + tj;
        #pragma unroll
        for (int r = 0; r < 16; ++r) {
            int hh = tr * 16 + r;
            t[hh][tj] = (j < D_DIM) ? W[(size_t)(h0 + hh) * D_DIM + j] : 0.0f;
        }
        __syncthreads();
        #pragma unroll
        for (int r = 0; r < 16; ++r) {
            int jj = tr * 16 + r;
            int jo = j0 + jj;
            if (jo < D_DIM) Wt2h[(size_t)jo * H_DIM + h0 + tj] = (_Float16)(t[tj][jj] * LOG2E);
        }
    }
}

// ---------- fused partial-sum + exclusive scan over f16 weights (consistent with k_main's wlds) ----------
__global__ void k_pscan(const _Float16* __restrict__ Wt2h, const int* __restrict__ x,
                        const float* __restrict__ c, _Float16* __restrict__ PA) {
    int b0 = blockIdx.x * BF;
    int h  = blockIdx.y * 256 + threadIdx.x;
    __shared__ float xs[BF][D_DIM];
    for (int q = threadIdx.x; q < BF * (D_DIM / 4); q += 256) {
        int bb = q / (D_DIM / 4), r = q % (D_DIM / 4);
        int4 xi = ((const int4*)(x + (size_t)(b0 + bb) * D_DIM))[r];
        float4 xf = make_float4((float)xi.x, (float)xi.y, (float)xi.z, (float)xi.w);
        *((float4*)&xs[bb][r * 4]) = xf;
    }
    float acc0 = c[h] * LOG2E, acc1 = acc0;
    __syncthreads();
    for (int t = 0; t < T_CH; ++t) {
        PA[((size_t)t * B_DIM + b0 + 0) * H_DIM + h] = (_Float16)acc0;
        PA[((size_t)t * B_DIM + b0 + 1) * H_DIM + h] = (_Float16)acc1;
        #pragma unroll
        for (int j = 0; j < G_CH; ++j) {
            float wv = (float)Wt2h[(size_t)(t * G_CH + j) * H_DIM + h];
            acc0 += xs[0][t * G_CH + j] * wv;
            acc1 += xs[1][t * G_CH + j] * wv;
        }
    }
}

// ---------- main fused kernel: barrier-free sigmoid/MFMA loop, block-end softmax ----------
__global__ __launch_bounds__(256, 2)
void k_main(const _Float16* __restrict__ VB, const _Float16* __restrict__ Wt2h,
            const _Float16* __restrict__ PA, const int* __restrict__ x,
            const float* __restrict__ bias, float* __restrict__ out) {
    int bt  = blockIdx.x;        // batch tile 0..15 (fast dim: VB L2 reuse)
    int tc  = blockIdx.y;        // chunk 0..97
    int tid = threadIdx.x;
    int w   = tid >> 6;          // wave 0..3 (K-split of H)
    int l   = tid & 63;
    int bl  = l & 15;            // MFMA A row == batch row within tile
    int kg  = l >> 4;            // 0..3
    int bg  = bt * BT + bl;
    int i0  = tc * G_CH;

    __shared__ __align__(16) _Float16 wlds[G_CH][H_DIM]; // 16 KB
    __shared__ float red[4][64][18];                     // 18.4 KB, stride-18: 2-way max (free)
    __shared__ float bs[G_CH][16];                       // 0.5 KB

    {   // stage bias chunk
        int ii = tid >> 4, n = tid & 15;
        if (ii < G_CH) bs[ii][n] = (n < NBIN) ? bias[(size_t)(i0 + ii) * NBIN + n] : 0.0f;
    }
    {   // stage Wt2h chunk rows i0..i0+7 (f16 direct copy, coalesced)
        #pragma unroll
        for (int r = 0; r < G_CH; ++r) {
            uint2 v = ((const uint2*)(Wt2h + (size_t)(i0 + r) * H_DIM))[tid];
            *((uint2*)&wlds[r][tid * 4]) = v;
        }
    }
    float xvf[G_CH];
    {
        const int4* xp = (const int4*)(x + (size_t)bg * D_DIM + i0);
        int4 x0 = xp[0], x1 = xp[1];
        xvf[0] = (float)x0.x; xvf[1] = (float)x0.y; xvf[2] = (float)x0.z; xvf[3] = (float)x0.w;
        xvf[4] = (float)x1.x; xvf[5] = (float)x1.y; xvf[6] = (float)x1.z; xvf[7] = (float)x1.w;
    }
    float a[8][8];
    {
        const _Float16* src = PA + ((size_t)tc * B_DIM + bg) * H_DIM + w * 256 + kg * 8;
        #pragma unroll
        for (int m = 0; m < 8; ++m) {
            half8_t av = *((const half8_t*)(src + m * 32));
            #pragma unroll
            for (int j = 0; j < 8; ++j) a[m][j] = (float)av[j];
        }
    }
    __syncthreads();   // B0: wlds/bs staged

    const uint4* vbbase = (const uint4*)VB;
    float4_t cf[G_CH];

    auto compute_ii = [&](int ii) {
        int i = i0 + ii;
        uint4 vb[8];
        const uint4* vbp = vbbase + ((size_t)i * 32 + w * 8) * 64 + l;
        #pragma unroll
        for (int m = 0; m < 8; ++m) vb[m] = vbp[m * 64];
        float xf = xvf[ii];
        float4_t cfr = {0.f, 0.f, 0.f, 0.f};
        #pragma unroll
        for (int m = 0; m < 8; ++m) {
            union { half8_t h8; uint u32[4]; } af;
            #pragma unroll
            for (int p = 0; p < 4; ++p) {
                float s0 = __builtin_amdgcn_rcpf(1.0f + __builtin_amdgcn_exp2f(-a[m][2 * p]));
                float s1 = __builtin_amdgcn_rcpf(1.0f + __builtin_amdgcn_exp2f(-a[m][2 * p + 1]));
                union { fp16x2_t v; uint u; } cv;
                cv.v = __builtin_amdgcn_cvt_pkrtz(s0, s1);
                af.u32[p] = cv.u;
            }
            union { half8_t h8; uint4 u; } bf;
            bf.u = vb[m];
            cfr = __builtin_amdgcn_mfma_f32_16x16x32_f16(af.h8, bf.h8, cfr, 0, 0, 0);
            half8_t wh = *((const half8_t*)&wlds[ii][w * 256 + kg * 8 + m * 32]);
            a[m][0] += xf * (float)wh[0]; a[m][1] += xf * (float)wh[1];
            a[m][2] += xf * (float)wh[2]; a[m][3] += xf * (float)wh[3];
            a[m][4] += xf * (float)wh[4]; a[m][5] += xf * (float)wh[5];
            a[m][6] += xf * (float)wh[6]; a[m][7] += xf * (float)wh[7];
        }
        cf[ii] = cfr;
    };

    auto softmax_store = [&](int half) {
        float p4[4];
        #pragma unroll
        for (int q = 0; q < 4; ++q) {
            int ii = half * 4 + q;
            float tot = red[0][l][q * 4 + w] + red[1][l][q * 4 + w]
                      + red[2][l][q * 4 + w] + red[3][l][q * 4 + w];
            float v = (bl < NBIN) ? tot + bs[ii][bl] : -3.0e38f;
            float vm = v;
            vm = fmaxf(vm, __shfl_xor(vm, 1));
            vm = fmaxf(vm, __shfl_xor(vm, 2));
            vm = fmaxf(vm, __shfl_xor(vm, 4));
            vm = fmaxf(vm, __shfl_xor(vm, 8));
            float e = __builtin_amdgcn_exp2f((v - vm) * LOG2E);
            float ss = e;
            ss += __shfl_xor(ss, 1); ss += __shfl_xor(ss, 2);
            ss += __shfl_xor(ss, 4); ss += __shfl_xor(ss, 8);
            p4[q] = e * __builtin_amdgcn_rcpf(ss);
        }
        if (bl < NBIN) {
            int b = bt * BT + kg * 4 + w;   // this thread's C row = batch row
            size_t base = ((size_t)b * NBIN + bl) * D_DIM + i0 + half * 4;
            float4 v = make_float4(p4[0], p4[1], p4[2], p4[3]);
            *((float4*)(out + base)) = v;
        }
    };

    // barrier-free compute, two-phase flush
    for (int q = 0; q < 4; ++q) compute_ii(q);
    #pragma unroll
    for (int q = 0; q < 4; ++q) {
        #pragma unroll
        for (int r = 0; r < 4; ++r) red[w][l][q * 4 + r] = cf[q][r];
    }
    __syncthreads();   // B1: half-0 partials visible
    for (int q = 0; q < 4; ++q) compute_ii(4 + q);
    softmax_store(0);
    __syncthreads();   // B2: all half-0 reads done
    #pragma unroll
    for (int q = 0; q < 4; ++q) {
        #pragma unroll
        for (int r = 0; r < 4; ++r) red[w][l][q * 4 + r] = cf[4 + q][r];
    }
    __syncthreads();   // B3: half-1 partials visible
    softmax_store(1);
}

extern "C" void kernel_launch(void* const* d_in, const int* in_sizes, int n_in,
                              void* d_out, int out_size, void* d_ws, size_t ws_size,
                              hipStream_t stream) {
    const int*   x    = (const int*)d_in[0];
    const float* W    = (const float*)d_in[1];
    const float* c    = (const float*)d_in[2];
    const float* V    = (const float*)d_in[3];
    const float* bias = (const float*)d_in[4];
    float* out = (float*)d_out;

    char* ws = (char*)d_ws;
    size_t off = 0;
    _Float16* Wt2h = (_Float16*)(ws + off);
    off += (size_t)D_DIM * H_DIM * sizeof(_Float16);
    off = (off + 255) & ~(size_t)255;
    _Float16* VB = (_Float16*)(ws + off);
    off += (size_t)D_DIM * 32 * 64 * 8 * sizeof(_Float16);
    off = (off + 255) & ~(size_t)255;
    _Float16* PA = (_Float16*)(ws + off);

    k_prep<<<dim3(D_DIM + 208), 256, 0, stream>>>(W, V, Wt2h, VB);
    k_pscan<<<dim3(B_DIM / BF, 4), 256, 0, stream>>>(Wt2h, x, c, PA);
    k_main<<<dim3(B_DIM / BT, T_CH), 256, 0, stream>>>(VB, Wt2h, PA, x, bias, out);
}